// Round 4
// baseline (446.734 us; speedup 1.0000x reference)
//
#include <hip/hip_runtime.h>

typedef unsigned short ushort_t;
typedef __attribute__((ext_vector_type(2))) float f32x2;
typedef __attribute__((ext_vector_type(8))) short bfrag;
typedef __attribute__((ext_vector_type(4))) float f32x4;

__device__ __forceinline__ float sigf(float x) { return 1.0f / (1.0f + __expf(-x)); }
__device__ __forceinline__ float tanhf_fast(float x) { return 1.0f - 2.0f / (__expf(2.0f * x) + 1.0f); }
__device__ __forceinline__ ushort_t f2bf(float f) {
    unsigned u = __float_as_uint(f);
    unsigned r = (u + 0x7fffu + ((u >> 16) & 1u)) >> 16;
    return (ushort_t)r;
}

// ---------------------------------------------------------------------------
// K0: batched prep — 4 weight transposes (w1s transpose eliminated: rnn now
// consumes att_w1s in original layout via per-thread register cache).
// Blocks: [0,64) enc_Wih, [64,128) dec_Wih, [128,144) w1t, [144,176) out_w.
// ---------------------------------------------------------------------------
__global__ void prep_kernel(const float* __restrict__ eW, float* __restrict__ eWT,
                            const float* __restrict__ dW, float* __restrict__ dWT,
                            const float* __restrict__ w1t, float* __restrict__ w1tT,
                            const float* __restrict__ ow, float* __restrict__ owT)
{
    int bid = blockIdx.x;
    int tid = threadIdx.x;
    __shared__ float tile[32][33];
    const float* in; float* outp; int C; int t;
    if (bid < 64)       { in = eW;  outp = eWT;  C = 128; t = bid; }
    else if (bid < 128) { in = dW;  outp = dWT;  C = 128; t = bid - 64; }
    else if (bid < 144) { in = w1t; outp = w1tT; C = 128; t = bid - 128; }
    else                { in = ow;  outp = owT;  C = 256; t = bid - 144; }
    int R = (bid < 128) ? 512 : 128;             // all dims exact multiples of 32
    int gx = C >> 5;
    int c0 = (t & (gx - 1)) * 32, r0 = (t / gx) * 32;
    int x = tid & 31, y = tid >> 5;
#pragma unroll
    for (int i = 0; i < 32; i += 8)
        tile[y + i][x] = in[(r0 + y + i) * C + c0 + x];
    __syncthreads();
#pragma unroll
    for (int i = 0; i < 32; i += 8)
        outp[(c0 + y + i) * R + r0 + x] = tile[x][y + i];
}

// ---------------------------------------------------------------------------
// K1: enc + dec input-gate precompute, 8 tokens per block (halves W traffic
// vs 4/block). Blocks [0,200) enc (1600=200*8), [200,396) dec (1568=196*8).
// ---------------------------------------------------------------------------
__global__ void __launch_bounds__(512) tok_gemv2_kernel(
    const float* __restrict__ embS, const int* __restrict__ src,
    const float* __restrict__ WTe,
    const float* __restrict__ bihE, const float* __restrict__ bhhE,
    float* __restrict__ gihE,
    const float* __restrict__ embT, const int* __restrict__ trg,
    const float* __restrict__ WTd,
    const float* __restrict__ bihD, const float* __restrict__ bhhD,
    float* __restrict__ gihD)
{
    __shared__ __align__(16) float xs[8 * 128];
    const float* X; const int* toks; int divv; const float* WT;
    const float* b1; const float* b2; float* out; int ntok; int n0;
    if (blockIdx.x < 200) {
        X = embS; toks = src; divv = 0;  WT = WTe; b1 = bihE; b2 = bhhE;
        out = gihE; ntok = 1600; n0 = blockIdx.x * 8;
    } else {
        X = embT; toks = trg; divv = 49; WT = WTd; b1 = bihD; b2 = bhhD;
        out = gihD; ntok = 1568; n0 = (blockIdx.x - 200) * 8;
    }
    int tid = threadIdx.x;
    for (int i = tid; i < 8 * 128; i += 512) {
        int tt = i >> 7, k = i & 127;
        int n = n0 + tt;
        if (n >= ntok) n = ntok - 1;
        int row;
        if (divv == 0) row = toks[n];
        else { int bb = n / divv; int t = n - bb * divv; row = toks[bb * (divv + 1) + t]; }
        xs[i] = X[row * 128 + k];
    }
    __syncthreads();
    int j = tid;
    float bias = b1[j] + b2[j];
    float acc[8] = {0.f, 0.f, 0.f, 0.f, 0.f, 0.f, 0.f, 0.f};
#pragma unroll 4
    for (int k4 = 0; k4 < 32; ++k4) {
        float w0 = WT[(k4 * 4 + 0) * 512 + j];
        float w1 = WT[(k4 * 4 + 1) * 512 + j];
        float w2_ = WT[(k4 * 4 + 2) * 512 + j];
        float w3 = WT[(k4 * 4 + 3) * 512 + j];
#pragma unroll
        for (int tt = 0; tt < 8; ++tt) {
            float4 v = ((const float4*)(xs + tt * 128))[k4];
            acc[tt] += v.x * w0 + v.y * w1 + v.z * w2_ + v.w * w3;
        }
    }
#pragma unroll
    for (int tt = 0; tt < 8; ++tt) {
        int n = n0 + tt;
        if (n < ntok) out[n * 512 + j] = bias + acc[tt];
    }
}

// ---------------------------------------------------------------------------
// K2: combined LSTM recurrences + FUSED att_src (encoder blocks).
// Blocks 0..31: encoder (T=50), 32..63: decoder (T=49).
// Whh row tid in 128 VGPRs; enc blocks additionally cache a 32-float slice of
// w1s in 8 VGPR-float4s and compute att_src[b][t-1] = b1s + w1s @ h_{t-1}
// inside the existing 2-barrier structure (partials before barrier 2, reduce
// in the tid<128 tail). Epilogue emits t = T-1.
// ---------------------------------------------------------------------------
__global__ void __launch_bounds__(512) rnn_kernel(const float* __restrict__ gih_enc,
                                                  const float* __restrict__ enc_Whh,
                                                  const float* __restrict__ gih_dec,
                                                  const float* __restrict__ dec_Whh,
                                                  const float* __restrict__ w1s,  // 128x128 original
                                                  const float* __restrict__ b1s,
                                                  float* __restrict__ enc_out,
                                                  float* __restrict__ hdec,
                                                  float* __restrict__ att_src)
{
    bool is_enc = blockIdx.x < 32;
    int b = is_enc ? blockIdx.x : blockIdx.x - 32;
    int T = is_enc ? 50 : 49;
    const float* gih = is_enc ? gih_enc : gih_dec;
    const float* Whh = is_enc ? enc_Whh : dec_Whh;
    float* hout = is_enc ? enc_out : hdec;

    int tid = threadIdx.x;
    int j = tid & 127, part = tid >> 7;   // att_src decomposition
    __shared__ __align__(16) float h[128];
    __shared__ float gates[512];
    __shared__ float asum[512];

    // cache Whh row `tid` in registers (128 VGPRs)
    float4 w4[32];
    const float4* wr = (const float4*)(Whh + tid * 128);
#pragma unroll
    for (int k = 0; k < 32; ++k) w4[k] = wr[k];

    // enc: cache w1s[j][part*32 .. +32) (8 float4 = 32 VGPRs) + bias
    float4 ws4[8];
    float b1sr = 0.f;
    if (is_enc) {
        const float4* wsr = (const float4*)(w1s + j * 128 + part * 32);
#pragma unroll
        for (int k = 0; k < 8; ++k) ws4[k] = wsr[k];
        if (tid < 128) b1sr = b1s[tid];
    }
    float* asb = att_src + b * 6400;

    float c = 0.f;
    if (tid < 128) h[tid] = 0.f;
    const float* gb = gih + b * T * 512 + tid;
    float gnext = gb[0];
    const float4* h4 = (const float4*)h;
    int gt = tid >> 7;  // 0:i 1:f 2:g 3:o (wave-uniform)

    for (int t = 0; t < T; ++t) {
        __syncthreads();                       // h_{t-1} visible
        float g0 = gnext;
        if (t + 1 < T) gnext = gb[(t + 1) * 512];  // prefetch (independent of h)
        f32x2 s0 = {0.f, 0.f}, s1 = {0.f, 0.f};
#pragma unroll
        for (int k = 0; k < 32; ++k) {
            float4 hv = h4[k];                 // ds_read_b128 broadcast
            f32x2 ha = {hv.x, hv.y}, hb = {hv.z, hv.w};
            f32x2 wa = {w4[k].x, w4[k].y}, wb = {w4[k].z, w4[k].w};
            s0 += ha * wa;                     // v_pk_fma_f32
            s1 += hb * wb;
        }
        float acc = g0 + s0.x + s0.y + s1.x + s1.y;
        gates[tid] = (gt == 2) ? tanhf_fast(acc) : sigf(acc);
        if (is_enc && t > 0) {
            // att_src partial for step t-1 (h still holds h_{t-1})
            f32x2 p0 = {0.f, 0.f}, p1 = {0.f, 0.f};
#pragma unroll
            for (int k = 0; k < 8; ++k) {
                float4 hv = h4[part * 8 + k];  // broadcast within wave
                f32x2 ha = {hv.x, hv.y}, hb = {hv.z, hv.w};
                f32x2 wa = {ws4[k].x, ws4[k].y}, wb = {ws4[k].z, ws4[k].w};
                p0 += ha * wa; p1 += hb * wb;
            }
            asum[tid] = p0.x + p0.y + p1.x + p1.y;
        }
        __syncthreads();
        if (tid < 128) {
            float ai = gates[tid], af = gates[128 + tid], ag = gates[256 + tid], ao = gates[384 + tid];
            c = af * c + ai * ag;
            float hn = ao * tanhf_fast(c);
            h[tid] = hn;
            hout[(b * T + t) * 128 + tid] = hn;
            if (is_enc && t > 0)
                asb[(t - 1) * 128 + tid] = b1sr + asum[tid] + asum[128 + tid]
                                         + asum[256 + tid] + asum[384 + tid];
        }
    }
    // epilogue: att_src for t = T-1 (encoder only; block-uniform branch)
    if (is_enc) {
        __syncthreads();                       // final h visible
        f32x2 p0 = {0.f, 0.f}, p1 = {0.f, 0.f};
#pragma unroll
        for (int k = 0; k < 8; ++k) {
            float4 hv = h4[part * 8 + k];
            f32x2 ha = {hv.x, hv.y}, hb = {hv.z, hv.w};
            f32x2 wa = {ws4[k].x, ws4[k].y}, wb = {ws4[k].z, ws4[k].w};
            p0 += ha * wa; p1 += hb * wb;
        }
        asum[tid] = p0.x + p0.y + p1.x + p1.y;
        __syncthreads();
        if (tid < 128)
            asb[49 * 128 + tid] = b1sr + asum[tid] + asum[128 + tid]
                                + asum[256 + tid] + asum[384 + tid];
    }
}

// ---------------------------------------------------------------------------
// K3: attention + output projection, TWO decoder steps per block (grid 25x32).
// ---------------------------------------------------------------------------
__global__ void __launch_bounds__(128) att_par_kernel(const float* __restrict__ hdec,
                                                      const float* __restrict__ att_src,
                                                      const float* __restrict__ enc_out,
                                                      const float* __restrict__ w1tT,   // 128x128
                                                      const float* __restrict__ b1t,
                                                      const float* __restrict__ w2,
                                                      const float* __restrict__ b2,
                                                      const float* __restrict__ out_wT, // 256x128
                                                      const float* __restrict__ out_b,
                                                      ushort_t* __restrict__ fin_bf)
{
    int b = blockIdx.y;
    int t0 = blockIdx.x * 2;
    int t1 = t0 + 1; if (t1 > 48) t1 = 48;   // edge: duplicate work, same stores
    int tid = threadIdx.x, lane = tid & 63, wv = tid >> 6;
    __shared__ __align__(16) float h0[128], h1[128];
    __shared__ __align__(16) float av0s[128], av1s[128];
    __shared__ float attt0[128], attt1[128];
    __shared__ float sc0[64], sc1[64];

    h0[tid] = hdec[(b * 49 + t0) * 128 + tid];
    h1[tid] = hdec[(b * 49 + t1) * 128 + tid];
    __syncthreads();
    const float4* h04 = (const float4*)h0;
    const float4* h14 = (const float4*)h1;

    // att_tgt for both t, shared weight loads
    {
        float acc0 = b1t[tid], acc1 = acc0;
#pragma unroll
        for (int k4 = 0; k4 < 32; ++k4) {
            float4 hv0 = h04[k4], hv1 = h14[k4];
            int k = k4 * 4;
            float wA = w1tT[(k + 0) * 128 + tid], wB = w1tT[(k + 1) * 128 + tid];
            float wC = w1tT[(k + 2) * 128 + tid], wD = w1tT[(k + 3) * 128 + tid];
            acc0 += hv0.x * wA + hv0.y * wB + hv0.z * wC + hv0.w * wD;
            acc1 += hv1.x * wA + hv1.y * wB + hv1.z * wC + hv1.w * wD;
        }
        attt0[tid] = acc0; attt1[tid] = acc1;
    }
    __syncthreads();
    // scores for both t, shared att_src loads
    {
        float w2a = w2[lane], w2b = w2[lane + 64], b2s = b2[0];
        float ta0 = attt0[lane], tb0 = attt0[lane + 64];
        float ta1 = attt1[lane], tb1 = attt1[lane + 64];
        const float* asb = att_src + b * 6400;
        for (int s = wv; s < 50; s += 2) {
            float lo = asb[s * 128 + lane], hi = asb[s * 128 + 64 + lane];
            float v0 = w2a * tanhf_fast(lo + ta0) + w2b * tanhf_fast(hi + tb0);
            float v1 = w2a * tanhf_fast(lo + ta1) + w2b * tanhf_fast(hi + tb1);
#pragma unroll
            for (int off = 32; off; off >>= 1) {
                v0 += __shfl_down(v0, off);
                v1 += __shfl_down(v1, off);
            }
            if (lane == 0) { sc0[s] = v0 + b2s; sc1[s] = v1 + b2s; }
        }
    }
    __syncthreads();
    // softmax over 50: wave0 -> sc0, wave1 -> sc1
    {
        float* scp = wv ? sc1 : sc0;
        float x = (lane < 50) ? scp[lane] : -1e30f;
        float m = x;
#pragma unroll
        for (int off = 32; off; off >>= 1) m = fmaxf(m, __shfl_xor(m, off));
        float e = (lane < 50) ? __expf(x - m) : 0.f;
        float ssum = e;
#pragma unroll
        for (int off = 32; off; off >>= 1) ssum += __shfl_xor(ssum, off);
        if (lane < 50) scp[lane] = e / ssum;
    }
    __syncthreads();
    // att_vec for both t, shared enc_out loads
    {
        const float* eob = enc_out + b * 6400;
        float a0 = 0.f, a1 = 0.f;
        for (int s = 0; s < 50; ++s) {
            float ev = eob[s * 128 + tid];
            a0 += sc0[s] * ev; a1 += sc1[s] * ev;
        }
        av0s[tid] = a0; av1s[tid] = a1;
    }
    __syncthreads();
    // final = tanh([h | attv] @ out_w^T + out_b) -> bf16, shared weight loads
    {
        const float4* a04 = (const float4*)av0s;
        const float4* a14 = (const float4*)av1s;
        float f0 = out_b[tid], f1 = f0;
#pragma unroll
        for (int k4 = 0; k4 < 32; ++k4) {
            float4 hv0 = h04[k4], hv1 = h14[k4];
            int k = k4 * 4;
            float wA = out_wT[(k + 0) * 128 + tid], wB = out_wT[(k + 1) * 128 + tid];
            float wC = out_wT[(k + 2) * 128 + tid], wD = out_wT[(k + 3) * 128 + tid];
            f0 += hv0.x * wA + hv0.y * wB + hv0.z * wC + hv0.w * wD;
            f1 += hv1.x * wA + hv1.y * wB + hv1.z * wC + hv1.w * wD;
        }
#pragma unroll
        for (int k4 = 0; k4 < 32; ++k4) {
            float4 v0 = a04[k4], v1 = a14[k4];
            int k = 128 + k4 * 4;
            float wA = out_wT[(k + 0) * 128 + tid], wB = out_wT[(k + 1) * 128 + tid];
            float wC = out_wT[(k + 2) * 128 + tid], wD = out_wT[(k + 3) * 128 + tid];
            f0 += v0.x * wA + v0.y * wB + v0.z * wC + v0.w * wD;
            f1 += v1.x * wA + v1.y * wB + v1.z * wC + v1.w * wD;
        }
        fin_bf[(b * 49 + t0) * 128 + tid] = f2bf(tanhf_fast(f0));
        fin_bf[(b * 49 + t1) * 128 + tid] = f2bf(tanhf_fast(f1));
    }
}

// ---------------------------------------------------------------------------
// K4: logits = final(1568x128) @ sm_w^T(128x32000) + sm_b, bf16 MFMA.
// B panel resident in regs (fused f32->bf16 cast); swapped-operand MFMA ->
// one dwordx4 store per tile. Nontemporal stores (via ext-vector f32x4 —
// __builtin_nontemporal_store rejects HIP_vector_type float4): the 200 MB
// output stream bypasses L2, keeping the A panel (re-read 500x) L2-resident.
// ---------------------------------------------------------------------------
__global__ void __launch_bounds__(256) logits_gemm_kernel(const ushort_t* __restrict__ A,
                                                          const float* __restrict__ Bw,
                                                          const float* __restrict__ bias,
                                                          float* __restrict__ out)
{
    int wv = threadIdx.x >> 6, lane = threadIdx.x & 63;
    int r = lane & 15, kq = (lane >> 4) * 8;
    int nb = blockIdx.x * 64 + wv * 16;      // this wave's 16-col tile

    // one-time: B tile f32 -> bf16 fragments in registers
    bfrag bf[4];
    {
        const float* bp = Bw + (size_t)(nb + r) * 128 + kq;
#pragma unroll
        for (int kk = 0; kk < 4; ++kk) {
            float4 lo = *(const float4*)(bp + kk * 32);
            float4 hi = *(const float4*)(bp + kk * 32 + 4);
            bfrag f;
            f[0] = (short)f2bf(lo.x); f[1] = (short)f2bf(lo.y);
            f[2] = (short)f2bf(lo.z); f[3] = (short)f2bf(lo.w);
            f[4] = (short)f2bf(hi.x); f[5] = (short)f2bf(hi.y);
            f[6] = (short)f2bf(hi.z); f[7] = (short)f2bf(hi.w);
            bf[kk] = f;
        }
    }
    int colq = (lane >> 4) * 4;
    float4 bs = *(const float4*)(bias + nb + colq);

    const ushort_t* ab = A + r * 128 + kq;
    bfrag a0 = *(const bfrag*)(ab);
    bfrag a1 = *(const bfrag*)(ab + 32);
    bfrag a2 = *(const bfrag*)(ab + 64);
    bfrag a3 = *(const bfrag*)(ab + 96);

    for (int mt = 0; mt < 98; ++mt) {
        bfrag c0 = a0, c1 = a1, c2 = a2, c3 = a3;
        if (mt < 97) {
            const ushort_t* np = ab + (mt + 1) * 16 * 128;
            a0 = *(const bfrag*)(np);
            a1 = *(const bfrag*)(np + 32);
            a2 = *(const bfrag*)(np + 64);
            a3 = *(const bfrag*)(np + 96);
        }
        f32x4 acc = {0.f, 0.f, 0.f, 0.f};
        acc = __builtin_amdgcn_mfma_f32_16x16x32_bf16(bf[0], c0, acc, 0, 0, 0);
        acc = __builtin_amdgcn_mfma_f32_16x16x32_bf16(bf[1], c1, acc, 0, 0, 0);
        acc = __builtin_amdgcn_mfma_f32_16x16x32_bf16(bf[2], c2, acc, 0, 0, 0);
        acc = __builtin_amdgcn_mfma_f32_16x16x32_bf16(bf[3], c3, acc, 0, 0, 0);
        int m = mt * 16 + r;
        f32x4 st = {acc[0] + bs.x, acc[1] + bs.y, acc[2] + bs.z, acc[3] + bs.w};
        __builtin_nontemporal_store(st, (f32x4*)(out + (size_t)m * 32000 + nb + colq));
    }
}

extern "C" void kernel_launch(void* const* d_in, const int* in_sizes, int n_in,
                              void* d_out, int out_size, void* d_ws, size_t ws_size,
                              hipStream_t stream)
{
    const int* src      = (const int*)d_in[0];
    const int* trg      = (const int*)d_in[1];
    const float* emb_src = (const float*)d_in[2];
    const float* emb_trg = (const float*)d_in[3];
    const float* enc_Wih = (const float*)d_in[4];
    const float* enc_Whh = (const float*)d_in[5];
    const float* enc_bih = (const float*)d_in[6];
    const float* enc_bhh = (const float*)d_in[7];
    const float* dec_Wih = (const float*)d_in[8];
    const float* dec_Whh = (const float*)d_in[9];
    const float* dec_bih = (const float*)d_in[10];
    const float* dec_bhh = (const float*)d_in[11];
    const float* att_w1s = (const float*)d_in[12];
    const float* att_b1s = (const float*)d_in[13];
    const float* att_w1t = (const float*)d_in[14];
    const float* att_b1t = (const float*)d_in[15];
    const float* att_w2  = (const float*)d_in[16];
    const float* att_b2  = (const float*)d_in[17];
    const float* out_w   = (const float*)d_in[18];
    const float* out_b   = (const float*)d_in[19];
    const float* sm_w    = (const float*)d_in[20];
    const float* sm_b    = (const float*)d_in[21];
    float* out = (float*)d_out;

    // Workspace layout. att_src has its OWN region (it is written DURING rnn —
    // overlapping gih_enc would race). fin_bf overlaps dead gih_dec.
    char* ws = (char*)d_ws;
    float*    gih_enc = (float*)(ws);                      // 3,276,800 (dead after rnn)
    float*    gih_dec = (float*)(ws + 3276800);            // 3,211,264 (dead after rnn)
    ushort_t* fin_bf  = (ushort_t*)(ws + 3276800);         //   401,408 (phase 4+, overlaps)
    float*    enc_out = (float*)(ws + 6488064);            //   819,200
    float*    hdec    = (float*)(ws + 7307264);            //   802,816
    float*    att_src = (float*)(ws + 8110080);            //   819,200 (live during rnn!)
    float*    w1tT    = (float*)(ws + 8929280);            //    65,536
    float*    outwT   = (float*)(ws + 8994816);            //   131,072
    float*    WihT_e  = (float*)(ws + 9125888);            //   262,144
    float*    WihT_d  = (float*)(ws + 9388032);            //   262,144 -> 9,650,176 total

    // K0: transposes (4 weights), one launch
    prep_kernel<<<176, 256, 0, stream>>>(enc_Wih, WihT_e, dec_Wih, WihT_d,
                                         att_w1t, w1tT, out_w, outwT);

    // K1: enc + dec input-gate precompute, 8 tokens/block
    tok_gemv2_kernel<<<396, 512, 0, stream>>>(emb_src, src, WihT_e, enc_bih, enc_bhh, gih_enc,
                                              emb_trg, trg, WihT_d, dec_bih, dec_bhh, gih_dec);

    // K2: both recurrences + fused att_src (enc blocks 0..31, dec 32..63)
    rnn_kernel<<<64, 512, 0, stream>>>(gih_enc, enc_Whh, gih_dec, dec_Whh,
                                       att_w1s, att_b1s, enc_out, hdec, att_src);

    // K3: attention + output projection, 2 decoder steps per block
    att_par_kernel<<<dim3(25, 32), 128, 0, stream>>>(hdec, att_src, enc_out,
                                                     w1tT, att_b1t, att_w2, att_b2,
                                                     outwT, out_b, fin_bf);

    // K4: big output GEMM (bf16 MFMA, fused sm_w cast, nontemporal stores)
    logits_gemm_kernel<<<500, 256, 0, stream>>>(fin_bf, sm_w, sm_b, out);
}

// Round 5
// 444.141 us; speedup vs baseline: 1.0058x; 1.0058x over previous
//
#include <hip/hip_runtime.h>

typedef unsigned short ushort_t;
typedef __attribute__((ext_vector_type(2))) float f32x2;
typedef __attribute__((ext_vector_type(8))) short bfrag;
typedef __attribute__((ext_vector_type(4))) float f32x4;

__device__ __forceinline__ float sigf(float x) { return 1.0f / (1.0f + __expf(-x)); }
__device__ __forceinline__ float tanhf_fast(float x) { return 1.0f - 2.0f / (__expf(2.0f * x) + 1.0f); }
__device__ __forceinline__ ushort_t f2bf(float f) {
    unsigned u = __float_as_uint(f);
    unsigned r = (u + 0x7fffu + ((u >> 16) & 1u)) >> 16;
    return (ushort_t)r;
}

// ---------------------------------------------------------------------------
// K0: batched prep — all 5 weight transposes in ONE launch.
// Blocks: [0,64) enc_Wih, [64,128) dec_Wih, [128,144) w1s, [144,160) w1t,
// [160,192) out_w.
// ---------------------------------------------------------------------------
__global__ void prep_kernel(const float* __restrict__ eW, float* __restrict__ eWT,
                            const float* __restrict__ dW, float* __restrict__ dWT,
                            const float* __restrict__ w1s, float* __restrict__ w1sT,
                            const float* __restrict__ w1t, float* __restrict__ w1tT,
                            const float* __restrict__ ow, float* __restrict__ owT)
{
    int bid = blockIdx.x;
    int tid = threadIdx.x;
    __shared__ float tile[32][33];
    const float* in; float* outp; int C; int t;
    if (bid < 64)       { in = eW;  outp = eWT;  C = 128; t = bid; }
    else if (bid < 128) { in = dW;  outp = dWT;  C = 128; t = bid - 64; }
    else if (bid < 144) { in = w1s; outp = w1sT; C = 128; t = bid - 128; }
    else if (bid < 160) { in = w1t; outp = w1tT; C = 128; t = bid - 144; }
    else                { in = ow;  outp = owT;  C = 256; t = bid - 160; }
    int R = (bid < 128) ? 512 : 128;             // all dims exact multiples of 32
    int gx = C >> 5;
    int c0 = (t & (gx - 1)) * 32, r0 = (t / gx) * 32;
    int x = tid & 31, y = tid >> 5;
#pragma unroll
    for (int i = 0; i < 32; i += 8)
        tile[y + i][x] = in[(r0 + y + i) * C + c0 + x];
    __syncthreads();
#pragma unroll
    for (int i = 0; i < 32; i += 8)
        outp[(c0 + y + i) * R + r0 + x] = tile[x][y + i];
}

// ---------------------------------------------------------------------------
// K1: enc + dec input-gate precompute, 8 tokens per block (halves W traffic
// vs 4/block). Blocks [0,200) enc (1600=200*8), [200,396) dec (1568=196*8).
// ---------------------------------------------------------------------------
__global__ void __launch_bounds__(512) tok_gemv2_kernel(
    const float* __restrict__ embS, const int* __restrict__ src,
    const float* __restrict__ WTe,
    const float* __restrict__ bihE, const float* __restrict__ bhhE,
    float* __restrict__ gihE,
    const float* __restrict__ embT, const int* __restrict__ trg,
    const float* __restrict__ WTd,
    const float* __restrict__ bihD, const float* __restrict__ bhhD,
    float* __restrict__ gihD)
{
    __shared__ __align__(16) float xs[8 * 128];
    const float* X; const int* toks; int divv; const float* WT;
    const float* b1; const float* b2; float* out; int ntok; int n0;
    if (blockIdx.x < 200) {
        X = embS; toks = src; divv = 0;  WT = WTe; b1 = bihE; b2 = bhhE;
        out = gihE; ntok = 1600; n0 = blockIdx.x * 8;
    } else {
        X = embT; toks = trg; divv = 49; WT = WTd; b1 = bihD; b2 = bhhD;
        out = gihD; ntok = 1568; n0 = (blockIdx.x - 200) * 8;
    }
    int tid = threadIdx.x;
    for (int i = tid; i < 8 * 128; i += 512) {
        int tt = i >> 7, k = i & 127;
        int n = n0 + tt;
        if (n >= ntok) n = ntok - 1;
        int row;
        if (divv == 0) row = toks[n];
        else { int bb = n / divv; int t = n - bb * divv; row = toks[bb * (divv + 1) + t]; }
        xs[i] = X[row * 128 + k];
    }
    __syncthreads();
    int j = tid;
    float bias = b1[j] + b2[j];
    float acc[8] = {0.f, 0.f, 0.f, 0.f, 0.f, 0.f, 0.f, 0.f};
#pragma unroll 4
    for (int k4 = 0; k4 < 32; ++k4) {
        float w0 = WT[(k4 * 4 + 0) * 512 + j];
        float w1 = WT[(k4 * 4 + 1) * 512 + j];
        float w2_ = WT[(k4 * 4 + 2) * 512 + j];
        float w3 = WT[(k4 * 4 + 3) * 512 + j];
#pragma unroll
        for (int tt = 0; tt < 8; ++tt) {
            float4 v = ((const float4*)(xs + tt * 128))[k4];
            acc[tt] += v.x * w0 + v.y * w1 + v.z * w2_ + v.w * w3;
        }
    }
#pragma unroll
    for (int tt = 0; tt < 8; ++tt) {
        int n = n0 + tt;
        if (n < ntok) out[n * 512 + j] = bias + acc[tt];
    }
}

// ---------------------------------------------------------------------------
// K2: combined LSTM recurrences (R2-proven form — NO fused att_src: the fusion
// added ~25% LDS instrs to the latency-bound serial per-step critical path).
// Blocks 0..31: encoder (T=50), 32..63: decoder (T=49).
// ---------------------------------------------------------------------------
__global__ void __launch_bounds__(512, 2) rnn_kernel(const float* __restrict__ gih_enc,
                                                     const float* __restrict__ enc_Whh,
                                                     const float* __restrict__ gih_dec,
                                                     const float* __restrict__ dec_Whh,
                                                     float* __restrict__ enc_out,
                                                     float* __restrict__ hdec)
{
    bool is_enc = blockIdx.x < 32;
    int b = is_enc ? blockIdx.x : blockIdx.x - 32;
    int T = is_enc ? 50 : 49;
    const float* gih = is_enc ? gih_enc : gih_dec;
    const float* Whh = is_enc ? enc_Whh : dec_Whh;
    float* hout = is_enc ? enc_out : hdec;

    int tid = threadIdx.x;
    __shared__ __align__(16) float h[128];
    __shared__ float gates[512];

    // cache Whh row `tid` in registers (128 VGPRs)
    float4 w4[32];
    const float4* wr = (const float4*)(Whh + tid * 128);
#pragma unroll
    for (int k = 0; k < 32; ++k) w4[k] = wr[k];

    float c = 0.f;
    if (tid < 128) h[tid] = 0.f;
    const float* gb = gih + b * T * 512 + tid;
    float gnext = gb[0];
    const float4* h4 = (const float4*)h;
    int gt = tid >> 7;  // 0:i 1:f 2:g 3:o (wave-uniform)

    for (int t = 0; t < T; ++t) {
        __syncthreads();
        float g0 = gnext;
        if (t + 1 < T) gnext = gb[(t + 1) * 512];  // prefetch (independent of h)
        f32x2 s0 = {0.f, 0.f}, s1 = {0.f, 0.f};
#pragma unroll
        for (int k = 0; k < 32; ++k) {
            float4 hv = h4[k];                 // ds_read_b128 broadcast
            f32x2 ha = {hv.x, hv.y}, hb = {hv.z, hv.w};
            f32x2 wa = {w4[k].x, w4[k].y}, wb = {w4[k].z, w4[k].w};
            s0 += ha * wa;                     // v_pk_fma_f32
            s1 += hb * wb;
        }
        float acc = g0 + s0.x + s0.y + s1.x + s1.y;
        gates[tid] = (gt == 2) ? tanhf_fast(acc) : sigf(acc);  // activation (512-wide)
        __syncthreads();
        if (tid < 128) {
            float ai = gates[tid], af = gates[128 + tid], ag = gates[256 + tid], ao = gates[384 + tid];
            c = af * c + ai * ag;
            float hn = ao * tanhf_fast(c);
            h[tid] = hn;
            hout[(b * T + t) * 128 + tid] = hn;
        }
    }
}

// ---------------------------------------------------------------------------
// K3: att_src = enc_out @ w1s^T + b1s (separate, fully parallel — R2-proven).
// 400 blocks x 128 threads, 4 rows each.
// ---------------------------------------------------------------------------
__global__ void __launch_bounds__(128) attsrc_gemv_kernel(const float* __restrict__ X,
                                                          const float* __restrict__ WT,
                                                          const float* __restrict__ b1,
                                                          float* __restrict__ out)
{
    __shared__ __align__(16) float xs[4 * 128];
    int n0 = blockIdx.x * 4;
    int tid = threadIdx.x;
    for (int i = tid; i < 4 * 128; i += 128) {
        int tt = i >> 7, k = i & 127;
        xs[i] = X[(n0 + tt) * 128 + k];
    }
    __syncthreads();
    float bias = b1[tid];
    const float4* x0 = (const float4*)(xs);
    const float4* x1 = (const float4*)(xs + 128);
    const float4* x2 = (const float4*)(xs + 256);
    const float4* x3 = (const float4*)(xs + 384);
    float a0 = 0.f, a1 = 0.f, a2 = 0.f, a3 = 0.f;
#pragma unroll 8
    for (int k4 = 0; k4 < 32; ++k4) {
        float4 v0 = x0[k4], v1 = x1[k4], v2 = x2[k4], v3 = x3[k4];
        float w0 = WT[(k4 * 4 + 0) * 128 + tid];
        float w1 = WT[(k4 * 4 + 1) * 128 + tid];
        float w2_ = WT[(k4 * 4 + 2) * 128 + tid];
        float w3 = WT[(k4 * 4 + 3) * 128 + tid];
        a0 += v0.x * w0 + v0.y * w1 + v0.z * w2_ + v0.w * w3;
        a1 += v1.x * w0 + v1.y * w1 + v1.z * w2_ + v1.w * w3;
        a2 += v2.x * w0 + v2.y * w1 + v2.z * w2_ + v2.w * w3;
        a3 += v3.x * w0 + v3.y * w1 + v3.z * w2_ + v3.w * w3;
    }
    out[(n0 + 0) * 128 + tid] = bias + a0;
    out[(n0 + 1) * 128 + tid] = bias + a1;
    out[(n0 + 2) * 128 + tid] = bias + a2;
    out[(n0 + 3) * 128 + tid] = bias + a3;
}

// ---------------------------------------------------------------------------
// K4: attention + output projection, FOUR decoder steps per block (grid 13x32).
// All four t share every w1tT/att_src/enc_out/out_wT load -> half the L2 read
// traffic of the 2-step version. Per-t summation order identical to R2.
// ---------------------------------------------------------------------------
__global__ void __launch_bounds__(128) att_par_kernel(const float* __restrict__ hdec,
                                                      const float* __restrict__ att_src,
                                                      const float* __restrict__ enc_out,
                                                      const float* __restrict__ w1tT,   // 128x128
                                                      const float* __restrict__ b1t,
                                                      const float* __restrict__ w2,
                                                      const float* __restrict__ b2,
                                                      const float* __restrict__ out_wT, // 256x128
                                                      const float* __restrict__ out_b,
                                                      ushort_t* __restrict__ fin_bf)
{
    int b = blockIdx.y;
    int tb = blockIdx.x * 4;
    int tid = threadIdx.x, lane = tid & 63, wv = tid >> 6;
    __shared__ __align__(16) float hs[4][128];
    __shared__ __align__(16) float avs[4][128];
    __shared__ float atts[4][128];
    __shared__ float scs[4][64];

    int tv0 = tb, tv1 = tb + 1, tv2 = tb + 2, tv3 = tb + 3;
    if (tv1 > 48) tv1 = 48;  // edge block duplicates t=48 (same stores, no race)
    if (tv2 > 48) tv2 = 48;
    if (tv3 > 48) tv3 = 48;
    hs[0][tid] = hdec[(b * 49 + tv0) * 128 + tid];
    hs[1][tid] = hdec[(b * 49 + tv1) * 128 + tid];
    hs[2][tid] = hdec[(b * 49 + tv2) * 128 + tid];
    hs[3][tid] = hdec[(b * 49 + tv3) * 128 + tid];
    __syncthreads();
    const float4* h04 = (const float4*)hs[0];
    const float4* h14 = (const float4*)hs[1];
    const float4* h24 = (const float4*)hs[2];
    const float4* h34 = (const float4*)hs[3];

    // att_tgt for all t, shared weight loads
    {
        float base = b1t[tid];
        float a0 = base, a1 = base, a2 = base, a3 = base;
#pragma unroll
        for (int k4 = 0; k4 < 32; ++k4) {
            int k = k4 * 4;
            float wA = w1tT[(k + 0) * 128 + tid], wB = w1tT[(k + 1) * 128 + tid];
            float wC = w1tT[(k + 2) * 128 + tid], wD = w1tT[(k + 3) * 128 + tid];
            float4 v0 = h04[k4], v1 = h14[k4], v2 = h24[k4], v3 = h34[k4];
            a0 += v0.x * wA + v0.y * wB + v0.z * wC + v0.w * wD;
            a1 += v1.x * wA + v1.y * wB + v1.z * wC + v1.w * wD;
            a2 += v2.x * wA + v2.y * wB + v2.z * wC + v2.w * wD;
            a3 += v3.x * wA + v3.y * wB + v3.z * wC + v3.w * wD;
        }
        atts[0][tid] = a0; atts[1][tid] = a1; atts[2][tid] = a2; atts[3][tid] = a3;
    }
    __syncthreads();
    // scores for all t, shared att_src loads
    {
        float w2a = w2[lane], w2b = w2[lane + 64], b2s = b2[0];
        float ta0 = atts[0][lane], tb0 = atts[0][lane + 64];
        float ta1 = atts[1][lane], tb1 = atts[1][lane + 64];
        float ta2 = atts[2][lane], tb2 = atts[2][lane + 64];
        float ta3 = atts[3][lane], tb3 = atts[3][lane + 64];
        const float* asb = att_src + b * 6400;
        for (int s = wv; s < 50; s += 2) {
            float lo = asb[s * 128 + lane], hi = asb[s * 128 + 64 + lane];
            float v0 = w2a * tanhf_fast(lo + ta0) + w2b * tanhf_fast(hi + tb0);
            float v1 = w2a * tanhf_fast(lo + ta1) + w2b * tanhf_fast(hi + tb1);
            float v2 = w2a * tanhf_fast(lo + ta2) + w2b * tanhf_fast(hi + tb2);
            float v3 = w2a * tanhf_fast(lo + ta3) + w2b * tanhf_fast(hi + tb3);
#pragma unroll
            for (int off = 32; off; off >>= 1) {
                v0 += __shfl_down(v0, off);
                v1 += __shfl_down(v1, off);
                v2 += __shfl_down(v2, off);
                v3 += __shfl_down(v3, off);
            }
            if (lane == 0) {
                scs[0][s] = v0 + b2s; scs[1][s] = v1 + b2s;
                scs[2][s] = v2 + b2s; scs[3][s] = v3 + b2s;
            }
        }
    }
    __syncthreads();
    // softmax over 50: wave wv handles slots {wv, wv+2}
    {
#pragma unroll
        for (int ii = 0; ii < 2; ++ii) {
            int i = wv + ii * 2;
            float x = (lane < 50) ? scs[i][lane] : -1e30f;
            float m = x;
#pragma unroll
            for (int off = 32; off; off >>= 1) m = fmaxf(m, __shfl_xor(m, off));
            float e = (lane < 50) ? __expf(x - m) : 0.f;
            float ssum = e;
#pragma unroll
            for (int off = 32; off; off >>= 1) ssum += __shfl_xor(ssum, off);
            if (lane < 50) scs[i][lane] = e / ssum;
        }
    }
    __syncthreads();
    // att_vec for all t, shared enc_out loads
    {
        const float* eob = enc_out + b * 6400;
        float a0 = 0.f, a1 = 0.f, a2 = 0.f, a3 = 0.f;
        for (int s = 0; s < 50; ++s) {
            float ev = eob[s * 128 + tid];
            a0 += scs[0][s] * ev; a1 += scs[1][s] * ev;
            a2 += scs[2][s] * ev; a3 += scs[3][s] * ev;
        }
        avs[0][tid] = a0; avs[1][tid] = a1; avs[2][tid] = a2; avs[3][tid] = a3;
    }
    __syncthreads();
    // final = tanh([h | attv] @ out_w^T + out_b) -> bf16, shared weight loads
    {
        const float4* a04 = (const float4*)avs[0];
        const float4* a14 = (const float4*)avs[1];
        const float4* a24 = (const float4*)avs[2];
        const float4* a34 = (const float4*)avs[3];
        float base = out_b[tid];
        float f0 = base, f1 = base, f2 = base, f3 = base;
#pragma unroll
        for (int k4 = 0; k4 < 32; ++k4) {
            int k = k4 * 4;
            float wA = out_wT[(k + 0) * 128 + tid], wB = out_wT[(k + 1) * 128 + tid];
            float wC = out_wT[(k + 2) * 128 + tid], wD = out_wT[(k + 3) * 128 + tid];
            float4 v0 = h04[k4], v1 = h14[k4], v2 = h24[k4], v3 = h34[k4];
            f0 += v0.x * wA + v0.y * wB + v0.z * wC + v0.w * wD;
            f1 += v1.x * wA + v1.y * wB + v1.z * wC + v1.w * wD;
            f2 += v2.x * wA + v2.y * wB + v2.z * wC + v2.w * wD;
            f3 += v3.x * wA + v3.y * wB + v3.z * wC + v3.w * wD;
        }
#pragma unroll
        for (int k4 = 0; k4 < 32; ++k4) {
            int k = 128 + k4 * 4;
            float wA = out_wT[(k + 0) * 128 + tid], wB = out_wT[(k + 1) * 128 + tid];
            float wC = out_wT[(k + 2) * 128 + tid], wD = out_wT[(k + 3) * 128 + tid];
            float4 v0 = a04[k4], v1 = a14[k4], v2 = a24[k4], v3 = a34[k4];
            f0 += v0.x * wA + v0.y * wB + v0.z * wC + v0.w * wD;
            f1 += v1.x * wA + v1.y * wB + v1.z * wC + v1.w * wD;
            f2 += v2.x * wA + v2.y * wB + v2.z * wC + v2.w * wD;
            f3 += v3.x * wA + v3.y * wB + v3.z * wC + v3.w * wD;
        }
        fin_bf[(b * 49 + tv0) * 128 + tid] = f2bf(tanhf_fast(f0));
        fin_bf[(b * 49 + tv1) * 128 + tid] = f2bf(tanhf_fast(f1));
        fin_bf[(b * 49 + tv2) * 128 + tid] = f2bf(tanhf_fast(f2));
        fin_bf[(b * 49 + tv3) * 128 + tid] = f2bf(tanhf_fast(f3));
    }
}

// ---------------------------------------------------------------------------
// K5: logits = final(1568x128) @ sm_w^T(128x32000) + sm_b, bf16 MFMA.
// B panel resident in regs (fused f32->bf16 cast); swapped-operand MFMA ->
// one dwordx4 store per tile. PLAIN stores (NT reverted: bypassing L2/L3
// write-back put the 200 MB stream on the synchronous HBM path — regression).
// ---------------------------------------------------------------------------
__global__ void __launch_bounds__(256) logits_gemm_kernel(const ushort_t* __restrict__ A,
                                                          const float* __restrict__ Bw,
                                                          const float* __restrict__ bias,
                                                          float* __restrict__ out)
{
    int wv = threadIdx.x >> 6, lane = threadIdx.x & 63;
    int r = lane & 15, kq = (lane >> 4) * 8;
    int nb = blockIdx.x * 64 + wv * 16;      // this wave's 16-col tile

    // one-time: B tile f32 -> bf16 fragments in registers
    bfrag bf[4];
    {
        const float* bp = Bw + (size_t)(nb + r) * 128 + kq;
#pragma unroll
        for (int kk = 0; kk < 4; ++kk) {
            float4 lo = *(const float4*)(bp + kk * 32);
            float4 hi = *(const float4*)(bp + kk * 32 + 4);
            bfrag f;
            f[0] = (short)f2bf(lo.x); f[1] = (short)f2bf(lo.y);
            f[2] = (short)f2bf(lo.z); f[3] = (short)f2bf(lo.w);
            f[4] = (short)f2bf(hi.x); f[5] = (short)f2bf(hi.y);
            f[6] = (short)f2bf(hi.z); f[7] = (short)f2bf(hi.w);
            bf[kk] = f;
        }
    }
    int colq = (lane >> 4) * 4;
    float4 bs = *(const float4*)(bias + nb + colq);

    const ushort_t* ab = A + r * 128 + kq;
    bfrag a0 = *(const bfrag*)(ab);
    bfrag a1 = *(const bfrag*)(ab + 32);
    bfrag a2 = *(const bfrag*)(ab + 64);
    bfrag a3 = *(const bfrag*)(ab + 96);

    for (int mt = 0; mt < 98; ++mt) {
        bfrag c0 = a0, c1 = a1, c2 = a2, c3 = a3;
        if (mt < 97) {
            const ushort_t* np = ab + (mt + 1) * 16 * 128;
            a0 = *(const bfrag*)(np);
            a1 = *(const bfrag*)(np + 32);
            a2 = *(const bfrag*)(np + 64);
            a3 = *(const bfrag*)(np + 96);
        }
        f32x4 acc = {0.f, 0.f, 0.f, 0.f};
        acc = __builtin_amdgcn_mfma_f32_16x16x32_bf16(bf[0], c0, acc, 0, 0, 0);
        acc = __builtin_amdgcn_mfma_f32_16x16x32_bf16(bf[1], c1, acc, 0, 0, 0);
        acc = __builtin_amdgcn_mfma_f32_16x16x32_bf16(bf[2], c2, acc, 0, 0, 0);
        acc = __builtin_amdgcn_mfma_f32_16x16x32_bf16(bf[3], c3, acc, 0, 0, 0);
        int m = mt * 16 + r;
        float4 st = {acc[0] + bs.x, acc[1] + bs.y, acc[2] + bs.z, acc[3] + bs.w};
        *(float4*)(out + (size_t)m * 32000 + nb + colq) = st;
    }
}

extern "C" void kernel_launch(void* const* d_in, const int* in_sizes, int n_in,
                              void* d_out, int out_size, void* d_ws, size_t ws_size,
                              hipStream_t stream)
{
    const int* src      = (const int*)d_in[0];
    const int* trg      = (const int*)d_in[1];
    const float* emb_src = (const float*)d_in[2];
    const float* emb_trg = (const float*)d_in[3];
    const float* enc_Wih = (const float*)d_in[4];
    const float* enc_Whh = (const float*)d_in[5];
    const float* enc_bih = (const float*)d_in[6];
    const float* enc_bhh = (const float*)d_in[7];
    const float* dec_Wih = (const float*)d_in[8];
    const float* dec_Whh = (const float*)d_in[9];
    const float* dec_bih = (const float*)d_in[10];
    const float* dec_bhh = (const float*)d_in[11];
    const float* att_w1s = (const float*)d_in[12];
    const float* att_b1s = (const float*)d_in[13];
    const float* att_w1t = (const float*)d_in[14];
    const float* att_b1t = (const float*)d_in[15];
    const float* att_w2  = (const float*)d_in[16];
    const float* att_b2  = (const float*)d_in[17];
    const float* out_w   = (const float*)d_in[18];
    const float* out_b   = (const float*)d_in[19];
    const float* sm_w    = (const float*)d_in[20];
    const float* sm_b    = (const float*)d_in[21];
    float* out = (float*)d_out;

    // Workspace layout (R2-proven): att_src overlaps dead gih_enc (written
    // AFTER rnn completes), fin_bf overlaps dead gih_dec.
    char* ws = (char*)d_ws;
    float*    gih_enc = (float*)(ws);                      // 3,276,800 (phase 1-2)
    float*    att_src = (float*)(ws);                      //   819,200 (phase 3+, overlaps)
    float*    gih_dec = (float*)(ws + 3276800);            // 3,211,264 (phase 1-2)
    ushort_t* fin_bf  = (ushort_t*)(ws + 3276800);         //   401,408 (phase 4+, overlaps)
    float*    enc_out = (float*)(ws + 6488064);            //   819,200
    float*    hdec    = (float*)(ws + 7307264);            //   802,816
    float*    WihT_e  = (float*)(ws + 8110080);            //   262,144
    float*    WihT_d  = (float*)(ws + 8372224);            //   262,144
    float*    w1sT    = (float*)(ws + 8634368);            //    65,536
    float*    w1tT    = (float*)(ws + 8699904);            //    65,536
    float*    outwT   = (float*)(ws + 8765440);            //   131,072 -> 8,896,512 total

    // K0: all 5 transposes, one launch
    prep_kernel<<<192, 256, 0, stream>>>(enc_Wih, WihT_e, dec_Wih, WihT_d,
                                         att_w1s, w1sT, att_w1t, w1tT,
                                         out_w, outwT);

    // K1: enc + dec input-gate precompute, 8 tokens/block
    tok_gemv2_kernel<<<396, 512, 0, stream>>>(emb_src, src, WihT_e, enc_bih, enc_bhh, gih_enc,
                                              emb_trg, trg, WihT_d, dec_bih, dec_bhh, gih_dec);

    // K2: both recurrences concurrently (enc blocks 0..31, dec 32..63)
    rnn_kernel<<<64, 512, 0, stream>>>(gih_enc, enc_Whh, gih_dec, dec_Whh, enc_out, hdec);

    // K3: att_src = enc_out @ w1s^T + b1s (parallel, 400 blocks)
    attsrc_gemv_kernel<<<400, 128, 0, stream>>>(enc_out, w1sT, att_b1s, att_src);

    // K4: attention + output projection, 4 decoder steps per block
    att_par_kernel<<<dim3(13, 32), 128, 0, stream>>>(hdec, att_src, enc_out,
                                                     w1tT, att_b1t, att_w2, att_b2,
                                                     outwT, out_b, fin_bf);

    // K5: big output GEMM (bf16 MFMA, fused sm_w cast, plain stores)
    logits_gemm_kernel<<<500, 256, 0, stream>>>(fin_bf, sm_w, sm_b, out);
}